// Round 20
// baseline (118.040 us; speedup 1.0000x reference)
//
#include <hip/hip_runtime.h>
#include <hip/hip_bf16.h>

typedef __bf16 bf16;
typedef __bf16 bf16x4 __attribute__((ext_vector_type(4)));
typedef __bf16 bf16x8 __attribute__((ext_vector_type(8)));
typedef float f32x4 __attribute__((ext_vector_type(4)));
typedef unsigned int u32x4 __attribute__((ext_vector_type(4)));

#define T_LEN 2048
#define NHEAD 16
#define DHEAD 64
#define CDIM 1024
#define NB 2

__device__ __forceinline__ void g2l16(const void* g, void* l) {
    __builtin_amdgcn_global_load_lds(
        (const __attribute__((address_space(1))) unsigned int*)g,
        (__attribute__((address_space(3))) unsigned int*)l, 16, 0, 0);
}

// native 2^x (v_exp_f32): inputs are base-2 logits
__device__ __forceinline__ float fexp2(float x) {
    float r;
    asm("v_exp_f32 %0, %1" : "=v"(r) : "v"(x));
    return r;
}

// stage a 64-row x 128-byte tile into linear LDS with XOR-swizzled content
// (source pre-swizzle, m173). 256 threads: two 16B chunks each.
__device__ __forceinline__ void stage_swz256(const bf16* __restrict__ g, size_t gstride,
                                             bf16* lds, int t) {
#pragma unroll
    for (int c = 0; c < 2; c++) {
        int off = c * 4096 + t * 16;           // phys byte offset in LDS (0..8191)
        int row = off >> 7;
        int lcol = (off & 127) ^ ((row & 7) << 4);
        g2l16(g + (size_t)row * gstride + (lcol >> 1), (char*)lds + off);
    }
}

__device__ __forceinline__ bf16x8 rd_swz(const bf16* lds, int row, int colB) {
    return *(const bf16x8*)((const char*)lds + row * 128 + (colB ^ ((row & 7) << 4)));
}

// ---------- fused prep: fp32->bf16 x3 + RoPE tables + mask (+block flags) ----------
__global__ __launch_bounds__(256) void prep_kernel(
    const float* __restrict__ x, const float* __restrict__ qkv_w,
    const float* __restrict__ out_w, const int* __restrict__ am,
    bf16* __restrict__ xb, bf16* __restrict__ wqb, bf16* __restrict__ wob,
    float* __restrict__ ct, float* __restrict__ st, float* __restrict__ mf,
    int* __restrict__ mflag) {
    int bid = blockIdx.x;
    if (bid < 4096) {                         // converts (block-uniform section)
        int i = bid * 256 + threadIdx.x;
        const float* src; bf16* dst; int j;
        if (i < 524288)      { src = x;     dst = xb;  j = i; }
        else if (i < 917504) { src = qkv_w; dst = wqb; j = i - 524288; }
        else                 { src = out_w; dst = wob; j = i - 917504; }
        const float4* p = (const float4*)src + (size_t)j * 2;
        float4 a = p[0], b = p[1];
        bf16x8 o;
        o[0] = (bf16)a.x; o[1] = (bf16)a.y; o[2] = (bf16)a.z; o[3] = (bf16)a.w;
        o[4] = (bf16)b.x; o[5] = (bf16)b.y; o[6] = (bf16)b.z; o[7] = (bf16)b.w;
        ((bf16x8*)dst)[j] = o;
    } else if (bid < 4608) {                  // RoPE tables
        int i = (bid - 4096) * 256 + threadIdx.x;   // i = t*64 + d
        int t = i >> 6, d = i & 63;
        float ex = (float)(2 * (d & 31)) / 64.0f;
        float inv = powf(10000.0f, -ex);
        float ang = (float)t * inv;
        ct[i] = cosf(ang);
        st[i] = sinf(ang);
    } else {                                  // key mask -> additive float + flags
        int i = (bid - 4608) * 256 + threadIdx.x;
        int v = am[i];
        mf[i] = (v != 0) ? 0.0f : -1e30f;
        unsigned long long bz = __ballot(v == 0);   // wave covers 64 consecutive i
        if ((threadIdx.x & 63) == 0) mflag[i >> 6] = (bz != 0) ? 1 : 0;
    }
}

// ---------- QKV GEMM: 128x128 tile, 8 waves, DOUBLE-BUFFERED (1 barrier/iter) ----------
__global__ __launch_bounds__(512, 4) void gemm_qkv_kernel(
    const bf16* __restrict__ xb, const bf16* __restrict__ wb,
    const float* __restrict__ bias,
    const float* __restrict__ ct, const float* __restrict__ st,
    bf16* __restrict__ qg, bf16* __restrict__ kg, bf16* __restrict__ vt) {
    __shared__ __align__(16) bf16 smem[2][2 * 128 * 64];   // 2 bufs x 32 KB
    int m0 = blockIdx.x * 128, n0 = blockIdx.y * 128;
    int t = threadIdx.x, w = t >> 6, l = t & 63;
    int wm = w & 3, wn = w >> 2;                // 4 M-strips x 2 N-halves
    int l15 = l & 15, lhi = l >> 4;
    f32x4 acc[2][4] = {};
    // prologue: stage k0=0 into buf 0
#pragma unroll
    for (int c = 0; c < 2; c++) {
        int off = c * 8192 + t * 16;
        int row = off >> 7;
        int lcol = (off & 127) ^ ((row & 7) << 4);
        g2l16(xb + (size_t)(m0 + row) * CDIM + (lcol >> 1), (char*)smem[0] + off);
        g2l16(wb + (size_t)(n0 + row) * CDIM + (lcol >> 1), (char*)(smem[0] + 128 * 64) + off);
    }
    __syncthreads();
    int cur = 0;
    for (int k0 = 0; k0 < CDIM; k0 += 64) {
        if (k0 + 64 < CDIM) {                   // issue prefetch of next K-tile
#pragma unroll
            for (int c = 0; c < 2; c++) {
                int off = c * 8192 + t * 16;
                int row = off >> 7;
                int lcol = (off & 127) ^ ((row & 7) << 4);
                g2l16(xb + (size_t)(m0 + row) * CDIM + k0 + 64 + (lcol >> 1),
                      (char*)smem[cur ^ 1] + off);
                g2l16(wb + (size_t)(n0 + row) * CDIM + k0 + 64 + (lcol >> 1),
                      (char*)(smem[cur ^ 1] + 128 * 64) + off);
            }
        }
        bf16* sA = smem[cur];
        bf16* sB = smem[cur] + 128 * 64;
#pragma unroll
        for (int ks = 0; ks < 2; ks++) {
            bf16x8 af[2], bfr[4];
#pragma unroll
            for (int mt = 0; mt < 2; mt++)
                af[mt] = rd_swz(sA, wm * 32 + mt * 16 + l15, ks * 64 + lhi * 16);
#pragma unroll
            for (int nt = 0; nt < 4; nt++)
                bfr[nt] = rd_swz(sB, wn * 64 + nt * 16 + l15, ks * 64 + lhi * 16);
#pragma unroll
            for (int mt = 0; mt < 2; mt++)
#pragma unroll
                for (int nt = 0; nt < 4; nt++)
                    acc[mt][nt] = __builtin_amdgcn_mfma_f32_16x16x32_bf16(
                        af[mt], bfr[nt], acc[mt][nt], 0, 0, 0);
        }
        __syncthreads();                        // one barrier/iter
        cur ^= 1;
    }
    int bb = m0 >> 11, tt0 = m0 & 2047;         // block never crosses batch
    if (n0 >= 2048) {
        // ---- V block (2 heads): bias + LDS transpose + coalesced store ----
        bf16* sT = (bf16*)smem;                 // [64 d][136 tt] = 17.4 KB
#pragma unroll
        for (int pass = 0; pass < 2; pass++) {
            __syncthreads();
            if (wn == pass) {
#pragma unroll
                for (int nt = 0; nt < 4; nt++) {
                    int dl = nt * 16 + l15;     // 0..63 within head
                    float cb = bias[n0 + pass * 64 + dl];
#pragma unroll
                    for (int mt = 0; mt < 2; mt++) {
                        bf16x4 pv;
#pragma unroll
                        for (int r = 0; r < 4; r++) pv[r] = (bf16)(acc[mt][nt][r] + cb);
                        *(bf16x4*)(sT + dl * 136 + wm * 32 + mt * 16 + lhi * 4) = pv;
                    }
                }
            }
            __syncthreads();
            int h_p = ((n0 & 1023) >> 6) + pass;
            size_t vbase = ((size_t)(bb * NHEAD + h_p)) * T_LEN * DHEAD + tt0;
#pragma unroll
            for (int c = 0; c < 2; c++) {
                int cid = c * 512 + t;
                int d = cid >> 4, ch = cid & 15;
                *(bf16x8*)(vt + vbase + (size_t)d * T_LEN + ch * 8) =
                    *(const bf16x8*)(sT + d * 136 + ch * 8);
            }
        }
        return;
    }
    // ---- Q/K block: bias + RoPE, [B][H][T][Dh] store ----
    int sec = n0 >> 10;                         // 0=Q 1=K (block-uniform)
    bf16* og = (sec == 0) ? qg : kg;
    float oscale = (sec == 0) ? 0.125f * 1.44269504f : 1.0f;
#pragma unroll
    for (int nt = 0; nt < 4; nt++) {
        int col = n0 + wn * 64 + nt * 16 + l15;
        int cc = col & 1023;
        int h = cc >> 6, d = cc & 63;
        float cb = bias[col];
        size_t hb = ((size_t)(bb * NHEAD + h)) * T_LEN * DHEAD;
#pragma unroll
        for (int mt = 0; mt < 2; mt++) {
#pragma unroll
            for (int r = 0; r < 4; r++) {
                int tt = tt0 + wm * 32 + mt * 16 + lhi * 4 + r;
                float v = acc[mt][nt][r] + cb;
                float p = __shfl_xor(v, 1);
                float cs = ct[tt * 64 + d], sn = st[tt * 64 + d];
                float o = (d & 1) ? (v * cs + p * sn) : (v * cs - p * sn);
                og[hb + (size_t)tt * DHEAD + d] = (bf16)(o * oscale);
            }
        }
    }
}

// ---------- flash attention: 4 waves x 32 q-rows (2 m-blocks, shared K/V
// fragments), QBLK=128, shift-free softmax. 512 blocks = 2/CU; co-resident
// pair qt = {pos, 15-pos} -> uniform 34 iters/CU. ----------
__global__ __launch_bounds__(256, 4) void attn_kernel(
    const bf16* __restrict__ qg, const bf16* __restrict__ kg, const bf16* __restrict__ vt,
    const float* __restrict__ maskf, const int* __restrict__ mflag,
    bf16* __restrict__ yb) {
    __shared__ __align__(16) bf16 sK[2][64 * 64];
    __shared__ __align__(16) bf16 sV[2][64 * 64];
    int lin = blockIdx.x;                 // 512 blocks
    int xcd = lin & 7, idx = lin >> 3;    // idx 0..63
    int group = idx >> 4, pos = idx & 15;
    int qt = (group & 2) ? (15 - pos) : pos;    // pair-balance (R6 lesson)
    int pair = xcd * 4 + group;           // 0..31
    int h = pair & 15, b = pair >> 4;
    int q0 = qt * 128;
    int t = threadIdx.x, w = t >> 6, l = t & 63;
    int l15 = l & 15, lhi = l >> 4;
    const size_t head_off = ((size_t)(b * NHEAD + h)) * T_LEN * DHEAD;
    const bf16* qb = qg + head_off;
    const bf16* kb = kg + head_off;
    const bf16* vb = vt + head_off;                 // [Dh][T]
    const float* mrow = maskf + b * T_LEN;
    const int* mfl = mflag + b * (T_LEN / 64);
    const int wq0 = q0 + w * 32;                    // wave's first q row (32-row strip)
    bf16x8 qf[2][2];                                // [m-block][ks]
#pragma unroll
    for (int mb = 0; mb < 2; mb++) {
        int qr = wq0 + mb * 16 + l15;
        qf[mb][0] = *(const bf16x8*)(qb + (size_t)qr * DHEAD + lhi * 8);
        qf[mb][1] = *(const bf16x8*)(qb + (size_t)qr * DHEAD + 32 + lhi * 8);
    }
    const u32x4 onesu = {0x3F803F80u, 0x3F803F80u, 0x3F803F80u, 0x3F803F80u};
    const bf16x8 ones8 = __builtin_bit_cast(bf16x8, onesu);
    f32x4 lsv[2] = {};                              // row-layout ls per m-block
    f32x4 accy[2][4] = {};
    stage_swz256(kb, DHEAD, sK[0], t);
    stage_swz256(vb, T_LEN, sV[0], t);
    __syncthreads();
    int cur = 0;
    const int kv_end = q0 + 64;                     // covers rows up to q0+127
    for (int kv0 = 0; kv0 <= kv_end; kv0 += 64) {
        if (kv0 + 64 <= kv_end) {                   // prefetch next tile
            stage_swz256(kb + (size_t)(kv0 + 64) * DHEAD, DHEAD, sK[cur ^ 1], t);
            stage_swz256(vb + (kv0 + 64), T_LEN, sV[cur ^ 1], t);
        }
        if (kv0 <= wq0 + 31) {                      // wave has unmasked work
            const bool act0 = (kv0 <= wq0 + 15);    // m-block 0 active
            // S^T = K Q^T, K fragment shared across both m-blocks
            f32x4 s[2][4] = {};
            __builtin_amdgcn_s_setprio(1);
#pragma unroll
            for (int c = 0; c < 4; c++)
#pragma unroll
                for (int ks = 0; ks < 2; ks++) {
                    bf16x8 kf = rd_swz(sK[cur], c * 16 + l15, ks * 64 + lhi * 16);
                    if (act0)
                        s[0][c] = __builtin_amdgcn_mfma_f32_16x16x32_bf16(kf, qf[0][ks], s[0][c], 0, 0, 0);
                    s[1][c] = __builtin_amdgcn_mfma_f32_16x16x32_bf16(kf, qf[1][ks], s[1][c], 0, 0, 0);
                }
            __builtin_amdgcn_s_setprio(0);
            int needmask = mfl[kv0 >> 6];           // uniform scalar load
#pragma unroll
            for (int mb = 0; mb < 2; mb++) {
                if (mb == 0 && !act0) continue;
                int mq0 = wq0 + mb * 16;
                bool diag = (kv0 + 63 > mq0);       // tile crosses strip's diagonal
                if (needmask || diag) {             // mask/causal adds (rare path)
                    int qrow_l = mq0 + l15;
#pragma unroll
                    for (int c = 0; c < 4; c++) {
                        float mpv[4] = {0.f, 0.f, 0.f, 0.f};
                        if (needmask) {
                            float4 mq = *(const float4*)(mrow + kv0 + c * 16 + lhi * 4);
                            mpv[0] = mq.x; mpv[1] = mq.y; mpv[2] = mq.z; mpv[3] = mq.w;
                        }
#pragma unroll
                        for (int r = 0; r < 4; r++) {
                            float sv = s[mb][c][r] + mpv[r];
                            if (diag && (kv0 + c * 16 + lhi * 4 + r > qrow_l)) sv = -1e30f;
                            s[mb][c][r] = sv;
                        }
                    }
                }
                // shift-free P = 2^s (scale cancels in accy/ls)
#pragma unroll
                for (int c = 0; c < 4; c++)
#pragma unroll
                    for (int r = 0; r < 4; r++) s[mb][c][r] = fexp2(s[mb][c][r]);
            }
            // PV: in-register relayout; V fragment shared across m-blocks
            __builtin_amdgcn_s_setprio(1);
#pragma unroll
            for (int g2 = 0; g2 < 2; g2++) {
                bf16x8 pvm[2];
#pragma unroll
                for (int mb = 0; mb < 2; mb++) {
                    if (mb == 0 && !act0) continue;
                    unsigned a0, a1, b0, b1;
                    asm("v_cvt_pk_bf16_f32 %0, %1, %2" : "=v"(a0) : "v"(s[mb][2 * g2][0]), "v"(s[mb][2 * g2][1]));
                    asm("v_cvt_pk_bf16_f32 %0, %1, %2" : "=v"(a1) : "v"(s[mb][2 * g2][2]), "v"(s[mb][2 * g2][3]));
                    asm("v_cvt_pk_bf16_f32 %0, %1, %2" : "=v"(b0) : "v"(s[mb][2 * g2 + 1][0]), "v"(s[mb][2 * g2 + 1][1]));
                    asm("v_cvt_pk_bf16_f32 %0, %1, %2" : "=v"(b1) : "v"(s[mb][2 * g2 + 1][2]), "v"(s[mb][2 * g2 + 1][3]));
                    asm("v_permlane32_swap_b32 %0, %1" : "+v"(a0), "+v"(b0));
                    asm("v_permlane16_swap_b32 %0, %1" : "+v"(a0), "+v"(b0));
                    asm("v_permlane32_swap_b32 %0, %1" : "+v"(a1), "+v"(b1));
                    asm("v_permlane16_swap_b32 %0, %1" : "+v"(a1), "+v"(b1));
                    u32x4 pu;
                    pu[0] = a0; pu[1] = a1; pu[2] = b0; pu[3] = b1;
                    pvm[mb] = __builtin_bit_cast(bf16x8, pu);
                    lsv[mb] = __builtin_amdgcn_mfma_f32_16x16x32_bf16(pvm[mb], ones8, lsv[mb], 0, 0, 0);
                }
#pragma unroll
                for (int dt = 0; dt < 4; dt++) {
                    bf16x8 vf = rd_swz(sV[cur], dt * 16 + l15, g2 * 64 + lhi * 16);
                    if (act0)
                        accy[0][dt] = __builtin_amdgcn_mfma_f32_16x16x32_bf16(pvm[0], vf, accy[0][dt], 0, 0, 0);
                    accy[1][dt] = __builtin_amdgcn_mfma_f32_16x16x32_bf16(pvm[1], vf, accy[1][dt], 0, 0, 0);
                }
            }
            __builtin_amdgcn_s_setprio(0);
        }
        __syncthreads();
        cur ^= 1;
    }
#pragma unroll
    for (int mb = 0; mb < 2; mb++)
#pragma unroll
        for (int r = 0; r < 4; r++) {
            float inv = lsv[mb][r] > 0.f ? 1.0f / lsv[mb][r] : 0.0f;   // lane-local
            int rowt = wq0 + mb * 16 + lhi * 4 + r;
            size_t obase = ((size_t)(b * T_LEN + rowt)) * CDIM + (size_t)h * DHEAD;
#pragma unroll
            for (int dt = 0; dt < 4; dt++)
                yb[obase + dt * 16 + l15] = (bf16)(accy[mb][dt][r] * inv);
        }
}

// ---------- output GEMM: 128x64 tiles, DOUBLE-BUFFERED (1 barrier/iter) ----------
__global__ __launch_bounds__(256) void gemm_out_kernel(
    const bf16* __restrict__ yb, const bf16* __restrict__ wb,
    const float* __restrict__ bias, float* __restrict__ out) {
    __shared__ __align__(16) bf16 smem[2][128 * 64 + 64 * 64];  // 2 x 24 KB
    int m0 = blockIdx.x * 128, n0 = blockIdx.y * 64;
    int t = threadIdx.x, w = t >> 6, l = t & 63;
    int wm = w >> 1, wn = w & 1;
    int l15 = l & 15, lhi = l >> 4;
    f32x4 acc[4][2] = {};
#pragma unroll
    for (int i = 0; i < 4; i++) {               // prologue stage k0=0
        int off = i * 4096 + t * 16;
        int row = off >> 7;
        int lcol = (off & 127) ^ ((row & 7) << 4);
        g2l16(yb + (size_t)(m0 + row) * CDIM + (lcol >> 1), (char*)smem[0] + off);
        if (i < 2)
            g2l16(wb + (size_t)(n0 + row) * CDIM + (lcol >> 1),
                  (char*)(smem[0] + 128 * 64) + off);
    }
    __syncthreads();
    int cur = 0;
    for (int k0 = 0; k0 < CDIM; k0 += 64) {
        if (k0 + 64 < CDIM) {
#pragma unroll
            for (int i = 0; i < 4; i++) {
                int off = i * 4096 + t * 16;
                int row = off >> 7;
                int lcol = (off & 127) ^ ((row & 7) << 4);
                g2l16(yb + (size_t)(m0 + row) * CDIM + k0 + 64 + (lcol >> 1),
                      (char*)smem[cur ^ 1] + off);
                if (i < 2)
                    g2l16(wb + (size_t)(n0 + row) * CDIM + k0 + 64 + (lcol >> 1),
                          (char*)(smem[cur ^ 1] + 128 * 64) + off);
            }
        }
        bf16* sA = smem[cur];
        bf16* sB = smem[cur] + 128 * 64;
#pragma unroll
        for (int ks = 0; ks < 2; ks++) {
            bf16x8 af[4], bfr[2];
#pragma unroll
            for (int mt = 0; mt < 4; mt++)
                af[mt] = rd_swz(sA, wm * 64 + mt * 16 + l15, ks * 64 + lhi * 16);
#pragma unroll
            for (int nt = 0; nt < 2; nt++)
                bfr[nt] = rd_swz(sB, wn * 32 + nt * 16 + l15, ks * 64 + lhi * 16);
#pragma unroll
            for (int mt = 0; mt < 4; mt++)
#pragma unroll
                for (int nt = 0; nt < 2; nt++)
                    acc[mt][nt] = __builtin_amdgcn_mfma_f32_16x16x32_bf16(
                        af[mt], bfr[nt], acc[mt][nt], 0, 0, 0);
        }
        __syncthreads();
        cur ^= 1;
    }
#pragma unroll
    for (int nt = 0; nt < 2; nt++) {
        int col = n0 + wn * 32 + nt * 16 + l15;
        float cb = bias[col];
#pragma unroll
        for (int mt = 0; mt < 4; mt++) {
#pragma unroll
            for (int r = 0; r < 4; r++) {
                int rowm = m0 + wm * 64 + mt * 16 + lhi * 4 + r;
                out[(size_t)rowm * CDIM + col] = acc[mt][nt][r] + cb;
            }
        }
    }
}

extern "C" void kernel_launch(void* const* d_in, const int* in_sizes, int n_in,
                              void* d_out, int out_size, void* d_ws, size_t ws_size,
                              hipStream_t stream) {
    const float* x      = (const float*)d_in[0];
    const int*   amask  = (const int*)d_in[1];
    const float* qkv_w  = (const float*)d_in[2];
    const float* qkv_b  = (const float*)d_in[3];
    const float* out_w  = (const float*)d_in[4];
    const float* out_b  = (const float*)d_in[5];
    float* out = (float*)d_out;

    char* ws = (char*)d_ws;
    bf16* xb  = (bf16*)(ws);                        // 8 MB   (4096x1024)
    bf16* wqb = (bf16*)(ws + (8ull  << 20));        // 6 MB   (3072x1024)
    bf16* wob = (bf16*)(ws + (14ull << 20));        // 2 MB   (1024x1024)
    bf16* qg  = (bf16*)(ws + (16ull << 20));        // 8 MB   [B,H,T,Dh]
    bf16* kg  = (bf16*)(ws + (24ull << 20));        // 8 MB   [B,H,T,Dh]
    bf16* vt  = (bf16*)(ws + (32ull << 20));        // 8 MB   [B,H,Dh,T]
    bf16* yb  = (bf16*)(ws + (40ull << 20));        // 8 MB   (4096x1024)
    float* ctab = (float*)(ws + (48ull << 20));     // 512 KB (2048x64)
    float* stab = (float*)(ws + (48ull << 20) + (1ull << 19));
    float* mkf  = (float*)(ws + (49ull << 20));     // 16 KB  (2x2048 floats)
    int*   mfg  = (int*)(ws + (49ull << 20) + (16ull << 10));  // 256 B (64 ints)

    prep_kernel<<<4624, 256, 0, stream>>>(x, qkv_w, out_w, amask,
                                          xb, wqb, wob, ctab, stab, mkf, mfg);
    gemm_qkv_kernel<<<dim3(32, 24), 512, 0, stream>>>(xb, wqb, qkv_b, ctab, stab, qg, kg, vt);
    attn_kernel<<<dim3(512), 256, 0, stream>>>(qg, kg, vt, mkf, mfg, yb);
    gemm_out_kernel<<<dim3(32, 16), 256, 0, stream>>>(yb, wob, out_b, out);
}

// Round 21
// 111.567 us; speedup vs baseline: 1.0580x; 1.0580x over previous
//
#include <hip/hip_runtime.h>
#include <hip/hip_bf16.h>

typedef __bf16 bf16;
typedef __bf16 bf16x4 __attribute__((ext_vector_type(4)));
typedef __bf16 bf16x8 __attribute__((ext_vector_type(8)));
typedef float f32x4 __attribute__((ext_vector_type(4)));
typedef unsigned int u32x4 __attribute__((ext_vector_type(4)));

#define T_LEN 2048
#define NHEAD 16
#define DHEAD 64
#define CDIM 1024
#define NB 2

__device__ __forceinline__ void g2l16(const void* g, void* l) {
    __builtin_amdgcn_global_load_lds(
        (const __attribute__((address_space(1))) unsigned int*)g,
        (__attribute__((address_space(3))) unsigned int*)l, 16, 0, 0);
}

// native 2^x (v_exp_f32): inputs are base-2 logits
__device__ __forceinline__ float fexp2(float x) {
    float r;
    asm("v_exp_f32 %0, %1" : "=v"(r) : "v"(x));
    return r;
}

// stage a 64-row x 128-byte tile into linear LDS with XOR-swizzled content
// (source pre-swizzle, m173). 256 threads: two 16B chunks each.
__device__ __forceinline__ void stage_swz256(const bf16* __restrict__ g, size_t gstride,
                                             bf16* lds, int t) {
#pragma unroll
    for (int c = 0; c < 2; c++) {
        int off = c * 4096 + t * 16;           // phys byte offset in LDS (0..8191)
        int row = off >> 7;
        int lcol = (off & 127) ^ ((row & 7) << 4);
        g2l16(g + (size_t)row * gstride + (lcol >> 1), (char*)lds + off);
    }
}

__device__ __forceinline__ bf16x8 rd_swz(const bf16* lds, int row, int colB) {
    return *(const bf16x8*)((const char*)lds + row * 128 + (colB ^ ((row & 7) << 4)));
}

// ---------- fused prep: fp32->bf16 x3 + RoPE tables + mask (+block flags) ----------
__global__ __launch_bounds__(256) void prep_kernel(
    const float* __restrict__ x, const float* __restrict__ qkv_w,
    const float* __restrict__ out_w, const int* __restrict__ am,
    bf16* __restrict__ xb, bf16* __restrict__ wqb, bf16* __restrict__ wob,
    float* __restrict__ ct, float* __restrict__ st, float* __restrict__ mf,
    int* __restrict__ mflag) {
    int bid = blockIdx.x;
    if (bid < 4096) {                         // converts (block-uniform section)
        int i = bid * 256 + threadIdx.x;
        const float* src; bf16* dst; int j;
        if (i < 524288)      { src = x;     dst = xb;  j = i; }
        else if (i < 917504) { src = qkv_w; dst = wqb; j = i - 524288; }
        else                 { src = out_w; dst = wob; j = i - 917504; }
        const float4* p = (const float4*)src + (size_t)j * 2;
        float4 a = p[0], b = p[1];
        bf16x8 o;
        o[0] = (bf16)a.x; o[1] = (bf16)a.y; o[2] = (bf16)a.z; o[3] = (bf16)a.w;
        o[4] = (bf16)b.x; o[5] = (bf16)b.y; o[6] = (bf16)b.z; o[7] = (bf16)b.w;
        ((bf16x8*)dst)[j] = o;
    } else if (bid < 4608) {                  // RoPE tables
        int i = (bid - 4096) * 256 + threadIdx.x;   // i = t*64 + d
        int t = i >> 6, d = i & 63;
        float ex = (float)(2 * (d & 31)) / 64.0f;
        float inv = powf(10000.0f, -ex);
        float ang = (float)t * inv;
        ct[i] = cosf(ang);
        st[i] = sinf(ang);
    } else {                                  // key mask -> additive float + flags
        int i = (bid - 4608) * 256 + threadIdx.x;
        int v = am[i];
        mf[i] = (v != 0) ? 0.0f : -1e30f;
        unsigned long long bz = __ballot(v == 0);   // wave covers 64 consecutive i
        if ((threadIdx.x & 63) == 0) mflag[i >> 6] = (bz != 0) ? 1 : 0;
    }
}

// ---------- QKV GEMM: 128x128 tile, 8 waves, DOUBLE-BUFFERED (1 barrier/iter) ----------
__global__ __launch_bounds__(512, 4) void gemm_qkv_kernel(
    const bf16* __restrict__ xb, const bf16* __restrict__ wb,
    const float* __restrict__ bias,
    const float* __restrict__ ct, const float* __restrict__ st,
    bf16* __restrict__ qg, bf16* __restrict__ kg, bf16* __restrict__ vt) {
    __shared__ __align__(16) bf16 smem[2][2 * 128 * 64];   // 2 bufs x 32 KB
    int m0 = blockIdx.x * 128, n0 = blockIdx.y * 128;
    int t = threadIdx.x, w = t >> 6, l = t & 63;
    int wm = w & 3, wn = w >> 2;                // 4 M-strips x 2 N-halves
    int l15 = l & 15, lhi = l >> 4;
    f32x4 acc[2][4] = {};
    // prologue: stage k0=0 into buf 0
#pragma unroll
    for (int c = 0; c < 2; c++) {
        int off = c * 8192 + t * 16;
        int row = off >> 7;
        int lcol = (off & 127) ^ ((row & 7) << 4);
        g2l16(xb + (size_t)(m0 + row) * CDIM + (lcol >> 1), (char*)smem[0] + off);
        g2l16(wb + (size_t)(n0 + row) * CDIM + (lcol >> 1), (char*)(smem[0] + 128 * 64) + off);
    }
    __syncthreads();
    int cur = 0;
    for (int k0 = 0; k0 < CDIM; k0 += 64) {
        if (k0 + 64 < CDIM) {                   // issue prefetch of next K-tile
#pragma unroll
            for (int c = 0; c < 2; c++) {
                int off = c * 8192 + t * 16;
                int row = off >> 7;
                int lcol = (off & 127) ^ ((row & 7) << 4);
                g2l16(xb + (size_t)(m0 + row) * CDIM + k0 + 64 + (lcol >> 1),
                      (char*)smem[cur ^ 1] + off);
                g2l16(wb + (size_t)(n0 + row) * CDIM + k0 + 64 + (lcol >> 1),
                      (char*)(smem[cur ^ 1] + 128 * 64) + off);
            }
        }
        bf16* sA = smem[cur];
        bf16* sB = smem[cur] + 128 * 64;
#pragma unroll
        for (int ks = 0; ks < 2; ks++) {
            bf16x8 af[2], bfr[4];
#pragma unroll
            for (int mt = 0; mt < 2; mt++)
                af[mt] = rd_swz(sA, wm * 32 + mt * 16 + l15, ks * 64 + lhi * 16);
#pragma unroll
            for (int nt = 0; nt < 4; nt++)
                bfr[nt] = rd_swz(sB, wn * 64 + nt * 16 + l15, ks * 64 + lhi * 16);
#pragma unroll
            for (int mt = 0; mt < 2; mt++)
#pragma unroll
                for (int nt = 0; nt < 4; nt++)
                    acc[mt][nt] = __builtin_amdgcn_mfma_f32_16x16x32_bf16(
                        af[mt], bfr[nt], acc[mt][nt], 0, 0, 0);
        }
        __syncthreads();                        // one barrier/iter
        cur ^= 1;
    }
    int bb = m0 >> 11, tt0 = m0 & 2047;         // block never crosses batch
    if (n0 >= 2048) {
        // ---- V block (2 heads): bias + LDS transpose + coalesced store ----
        bf16* sT = (bf16*)smem;                 // [64 d][136 tt] = 17.4 KB
#pragma unroll
        for (int pass = 0; pass < 2; pass++) {
            __syncthreads();
            if (wn == pass) {
#pragma unroll
                for (int nt = 0; nt < 4; nt++) {
                    int dl = nt * 16 + l15;     // 0..63 within head
                    float cb = bias[n0 + pass * 64 + dl];
#pragma unroll
                    for (int mt = 0; mt < 2; mt++) {
                        bf16x4 pv;
#pragma unroll
                        for (int r = 0; r < 4; r++) pv[r] = (bf16)(acc[mt][nt][r] + cb);
                        *(bf16x4*)(sT + dl * 136 + wm * 32 + mt * 16 + lhi * 4) = pv;
                    }
                }
            }
            __syncthreads();
            int h_p = ((n0 & 1023) >> 6) + pass;
            size_t vbase = ((size_t)(bb * NHEAD + h_p)) * T_LEN * DHEAD + tt0;
#pragma unroll
            for (int c = 0; c < 2; c++) {
                int cid = c * 512 + t;
                int d = cid >> 4, ch = cid & 15;
                *(bf16x8*)(vt + vbase + (size_t)d * T_LEN + ch * 8) =
                    *(const bf16x8*)(sT + d * 136 + ch * 8);
            }
        }
        return;
    }
    // ---- Q/K block: bias + RoPE, [B][H][T][Dh] store ----
    int sec = n0 >> 10;                         // 0=Q 1=K (block-uniform)
    bf16* og = (sec == 0) ? qg : kg;
    float oscale = (sec == 0) ? 0.125f * 1.44269504f : 1.0f;
#pragma unroll
    for (int nt = 0; nt < 4; nt++) {
        int col = n0 + wn * 64 + nt * 16 + l15;
        int cc = col & 1023;
        int h = cc >> 6, d = cc & 63;
        float cb = bias[col];
        size_t hb = ((size_t)(bb * NHEAD + h)) * T_LEN * DHEAD;
#pragma unroll
        for (int mt = 0; mt < 2; mt++) {
#pragma unroll
            for (int r = 0; r < 4; r++) {
                int tt = tt0 + wm * 32 + mt * 16 + lhi * 4 + r;
                float v = acc[mt][nt][r] + cb;
                float p = __shfl_xor(v, 1);
                float cs = ct[tt * 64 + d], sn = st[tt * 64 + d];
                float o = (d & 1) ? (v * cs + p * sn) : (v * cs - p * sn);
                og[hb + (size_t)tt * DHEAD + d] = (bf16)(o * oscale);
            }
        }
    }
}

// ---------- flash attention: 4 waves x 32 q-rows (2 m-blocks, shared K/V
// fragments), QBLK=128, shift-free softmax. 512 blocks = 2/CU; co-resident
// pair qt = {pos, 15-pos} -> uniform 34 iters/CU.
// launch_bounds(256,2): 256-reg/wave cap. (256,4) split the unified file
// 64 arch + 64 acc -> ~110 live arch VGPRs spilled ~5 MB/dispatch (R20). ----------
__global__ __launch_bounds__(256, 2) void attn_kernel(
    const bf16* __restrict__ qg, const bf16* __restrict__ kg, const bf16* __restrict__ vt,
    const float* __restrict__ maskf, const int* __restrict__ mflag,
    bf16* __restrict__ yb) {
    __shared__ __align__(16) bf16 sK[2][64 * 64];
    __shared__ __align__(16) bf16 sV[2][64 * 64];
    int lin = blockIdx.x;                 // 512 blocks
    int xcd = lin & 7, idx = lin >> 3;    // idx 0..63
    int group = idx >> 4, pos = idx & 15;
    int qt = (group & 2) ? (15 - pos) : pos;    // pair-balance (R6 lesson)
    int pair = xcd * 4 + group;           // 0..31
    int h = pair & 15, b = pair >> 4;
    int q0 = qt * 128;
    int t = threadIdx.x, w = t >> 6, l = t & 63;
    int l15 = l & 15, lhi = l >> 4;
    const size_t head_off = ((size_t)(b * NHEAD + h)) * T_LEN * DHEAD;
    const bf16* qb = qg + head_off;
    const bf16* kb = kg + head_off;
    const bf16* vb = vt + head_off;                 // [Dh][T]
    const float* mrow = maskf + b * T_LEN;
    const int* mfl = mflag + b * (T_LEN / 64);
    const int wq0 = q0 + w * 32;                    // wave's first q row (32-row strip)
    bf16x8 qf[2][2];                                // [m-block][ks]
#pragma unroll
    for (int mb = 0; mb < 2; mb++) {
        int qr = wq0 + mb * 16 + l15;
        qf[mb][0] = *(const bf16x8*)(qb + (size_t)qr * DHEAD + lhi * 8);
        qf[mb][1] = *(const bf16x8*)(qb + (size_t)qr * DHEAD + 32 + lhi * 8);
    }
    const u32x4 onesu = {0x3F803F80u, 0x3F803F80u, 0x3F803F80u, 0x3F803F80u};
    const bf16x8 ones8 = __builtin_bit_cast(bf16x8, onesu);
    f32x4 lsv[2] = {};                              // row-layout ls per m-block
    f32x4 accy[2][4] = {};
    stage_swz256(kb, DHEAD, sK[0], t);
    stage_swz256(vb, T_LEN, sV[0], t);
    __syncthreads();
    int cur = 0;
    const int kv_end = q0 + 64;                     // covers rows up to q0+127
    for (int kv0 = 0; kv0 <= kv_end; kv0 += 64) {
        if (kv0 + 64 <= kv_end) {                   // prefetch next tile
            stage_swz256(kb + (size_t)(kv0 + 64) * DHEAD, DHEAD, sK[cur ^ 1], t);
            stage_swz256(vb + (kv0 + 64), T_LEN, sV[cur ^ 1], t);
        }
        if (kv0 <= wq0 + 31) {                      // wave has unmasked work
            const bool act0 = (kv0 <= wq0 + 15);    // m-block 0 active
            // S^T = K Q^T, K fragment shared across both m-blocks
            f32x4 s[2][4] = {};
            __builtin_amdgcn_s_setprio(1);
#pragma unroll
            for (int c = 0; c < 4; c++)
#pragma unroll
                for (int ks = 0; ks < 2; ks++) {
                    bf16x8 kf = rd_swz(sK[cur], c * 16 + l15, ks * 64 + lhi * 16);
                    if (act0)
                        s[0][c] = __builtin_amdgcn_mfma_f32_16x16x32_bf16(kf, qf[0][ks], s[0][c], 0, 0, 0);
                    s[1][c] = __builtin_amdgcn_mfma_f32_16x16x32_bf16(kf, qf[1][ks], s[1][c], 0, 0, 0);
                }
            __builtin_amdgcn_s_setprio(0);
            int needmask = mfl[kv0 >> 6];           // uniform scalar load
#pragma unroll
            for (int mb = 0; mb < 2; mb++) {
                if (mb == 0 && !act0) continue;
                int mq0 = wq0 + mb * 16;
                bool diag = (kv0 + 63 > mq0);       // tile crosses strip's diagonal
                if (needmask || diag) {             // mask/causal adds (rare path)
                    int qrow_l = mq0 + l15;
#pragma unroll
                    for (int c = 0; c < 4; c++) {
                        float mpv[4] = {0.f, 0.f, 0.f, 0.f};
                        if (needmask) {
                            float4 mq = *(const float4*)(mrow + kv0 + c * 16 + lhi * 4);
                            mpv[0] = mq.x; mpv[1] = mq.y; mpv[2] = mq.z; mpv[3] = mq.w;
                        }
#pragma unroll
                        for (int r = 0; r < 4; r++) {
                            float sv = s[mb][c][r] + mpv[r];
                            if (diag && (kv0 + c * 16 + lhi * 4 + r > qrow_l)) sv = -1e30f;
                            s[mb][c][r] = sv;
                        }
                    }
                }
                // shift-free P = 2^s (scale cancels in accy/ls)
#pragma unroll
                for (int c = 0; c < 4; c++)
#pragma unroll
                    for (int r = 0; r < 4; r++) s[mb][c][r] = fexp2(s[mb][c][r]);
            }
            // PV: in-register relayout; V fragment shared across m-blocks
            __builtin_amdgcn_s_setprio(1);
#pragma unroll
            for (int g2 = 0; g2 < 2; g2++) {
                bf16x8 pvm[2];
#pragma unroll
                for (int mb = 0; mb < 2; mb++) {
                    if (mb == 0 && !act0) continue;
                    unsigned a0, a1, b0, b1;
                    asm("v_cvt_pk_bf16_f32 %0, %1, %2" : "=v"(a0) : "v"(s[mb][2 * g2][0]), "v"(s[mb][2 * g2][1]));
                    asm("v_cvt_pk_bf16_f32 %0, %1, %2" : "=v"(a1) : "v"(s[mb][2 * g2][2]), "v"(s[mb][2 * g2][3]));
                    asm("v_cvt_pk_bf16_f32 %0, %1, %2" : "=v"(b0) : "v"(s[mb][2 * g2 + 1][0]), "v"(s[mb][2 * g2 + 1][1]));
                    asm("v_cvt_pk_bf16_f32 %0, %1, %2" : "=v"(b1) : "v"(s[mb][2 * g2 + 1][2]), "v"(s[mb][2 * g2 + 1][3]));
                    asm("v_permlane32_swap_b32 %0, %1" : "+v"(a0), "+v"(b0));
                    asm("v_permlane16_swap_b32 %0, %1" : "+v"(a0), "+v"(b0));
                    asm("v_permlane32_swap_b32 %0, %1" : "+v"(a1), "+v"(b1));
                    asm("v_permlane16_swap_b32 %0, %1" : "+v"(a1), "+v"(b1));
                    u32x4 pu;
                    pu[0] = a0; pu[1] = a1; pu[2] = b0; pu[3] = b1;
                    pvm[mb] = __builtin_bit_cast(bf16x8, pu);
                    lsv[mb] = __builtin_amdgcn_mfma_f32_16x16x32_bf16(pvm[mb], ones8, lsv[mb], 0, 0, 0);
                }
#pragma unroll
                for (int dt = 0; dt < 4; dt++) {
                    bf16x8 vf = rd_swz(sV[cur], dt * 16 + l15, g2 * 64 + lhi * 16);
                    if (act0)
                        accy[0][dt] = __builtin_amdgcn_mfma_f32_16x16x32_bf16(pvm[0], vf, accy[0][dt], 0, 0, 0);
                    accy[1][dt] = __builtin_amdgcn_mfma_f32_16x16x32_bf16(pvm[1], vf, accy[1][dt], 0, 0, 0);
                }
            }
            __builtin_amdgcn_s_setprio(0);
        }
        __syncthreads();
        cur ^= 1;
    }
#pragma unroll
    for (int mb = 0; mb < 2; mb++)
#pragma unroll
        for (int r = 0; r < 4; r++) {
            float inv = lsv[mb][r] > 0.f ? 1.0f / lsv[mb][r] : 0.0f;   // lane-local
            int rowt = wq0 + mb * 16 + lhi * 4 + r;
            size_t obase = ((size_t)(b * T_LEN + rowt)) * CDIM + (size_t)h * DHEAD;
#pragma unroll
            for (int dt = 0; dt < 4; dt++)
                yb[obase + dt * 16 + l15] = (bf16)(accy[mb][dt][r] * inv);
        }
}

// ---------- output GEMM: 128x64 tiles, DOUBLE-BUFFERED (1 barrier/iter) ----------
__global__ __launch_bounds__(256) void gemm_out_kernel(
    const bf16* __restrict__ yb, const bf16* __restrict__ wb,
    const float* __restrict__ bias, float* __restrict__ out) {
    __shared__ __align__(16) bf16 smem[2][128 * 64 + 64 * 64];  // 2 x 24 KB
    int m0 = blockIdx.x * 128, n0 = blockIdx.y * 64;
    int t = threadIdx.x, w = t >> 6, l = t & 63;
    int wm = w >> 1, wn = w & 1;
    int l15 = l & 15, lhi = l >> 4;
    f32x4 acc[4][2] = {};
#pragma unroll
    for (int i = 0; i < 4; i++) {               // prologue stage k0=0
        int off = i * 4096 + t * 16;
        int row = off >> 7;
        int lcol = (off & 127) ^ ((row & 7) << 4);
        g2l16(yb + (size_t)(m0 + row) * CDIM + (lcol >> 1), (char*)smem[0] + off);
        if (i < 2)
            g2l16(wb + (size_t)(n0 + row) * CDIM + (lcol >> 1),
                  (char*)(smem[0] + 128 * 64) + off);
    }
    __syncthreads();
    int cur = 0;
    for (int k0 = 0; k0 < CDIM; k0 += 64) {
        if (k0 + 64 < CDIM) {
#pragma unroll
            for (int i = 0; i < 4; i++) {
                int off = i * 4096 + t * 16;
                int row = off >> 7;
                int lcol = (off & 127) ^ ((row & 7) << 4);
                g2l16(yb + (size_t)(m0 + row) * CDIM + k0 + 64 + (lcol >> 1),
                      (char*)smem[cur ^ 1] + off);
                if (i < 2)
                    g2l16(wb + (size_t)(n0 + row) * CDIM + k0 + 64 + (lcol >> 1),
                          (char*)(smem[cur ^ 1] + 128 * 64) + off);
            }
        }
        bf16* sA = smem[cur];
        bf16* sB = smem[cur] + 128 * 64;
#pragma unroll
        for (int ks = 0; ks < 2; ks++) {
            bf16x8 af[4], bfr[2];
#pragma unroll
            for (int mt = 0; mt < 4; mt++)
                af[mt] = rd_swz(sA, wm * 64 + mt * 16 + l15, ks * 64 + lhi * 16);
#pragma unroll
            for (int nt = 0; nt < 2; nt++)
                bfr[nt] = rd_swz(sB, wn * 32 + nt * 16 + l15, ks * 64 + lhi * 16);
#pragma unroll
            for (int mt = 0; mt < 4; mt++)
#pragma unroll
                for (int nt = 0; nt < 2; nt++)
                    acc[mt][nt] = __builtin_amdgcn_mfma_f32_16x16x32_bf16(
                        af[mt], bfr[nt], acc[mt][nt], 0, 0, 0);
        }
        __syncthreads();
        cur ^= 1;
    }
#pragma unroll
    for (int nt = 0; nt < 2; nt++) {
        int col = n0 + wn * 32 + nt * 16 + l15;
        float cb = bias[col];
#pragma unroll
        for (int mt = 0; mt < 4; mt++) {
#pragma unroll
            for (int r = 0; r < 4; r++) {
                int rowm = m0 + wm * 64 + mt * 16 + lhi * 4 + r;
                out[(size_t)rowm * CDIM + col] = acc[mt][nt][r] + cb;
            }
        }
    }
}

extern "C" void kernel_launch(void* const* d_in, const int* in_sizes, int n_in,
                              void* d_out, int out_size, void* d_ws, size_t ws_size,
                              hipStream_t stream) {
    const float* x      = (const float*)d_in[0];
    const int*   amask  = (const int*)d_in[1];
    const float* qkv_w  = (const float*)d_in[2];
    const float* qkv_b  = (const float*)d_in[3];
    const float* out_w  = (const float*)d_in[4];
    const float* out_b  = (const float*)d_in[5];
    float* out = (float*)d_out;

    char* ws = (char*)d_ws;
    bf16* xb  = (bf16*)(ws);                        // 8 MB   (4096x1024)
    bf16* wqb = (bf16*)(ws + (8ull  << 20));        // 6 MB   (3072x1024)
    bf16* wob = (bf16*)(ws + (14ull << 20));        // 2 MB   (1024x1024)
    bf16* qg  = (bf16*)(ws + (16ull << 20));        // 8 MB   [B,H,T,Dh]
    bf16* kg  = (bf16*)(ws + (24ull << 20));        // 8 MB   [B,H,T,Dh]
    bf16* vt  = (bf16*)(ws + (32ull << 20));        // 8 MB   [B,H,Dh,T]
    bf16* yb  = (bf16*)(ws + (40ull << 20));        // 8 MB   (4096x1024)
    float* ctab = (float*)(ws + (48ull << 20));     // 512 KB (2048x64)
    float* stab = (float*)(ws + (48ull << 20) + (1ull << 19));
    float* mkf  = (float*)(ws + (49ull << 20));     // 16 KB  (2x2048 floats)
    int*   mfg  = (int*)(ws + (49ull << 20) + (16ull << 10));  // 256 B (64 ints)

    prep_kernel<<<4624, 256, 0, stream>>>(x, qkv_w, out_w, amask,
                                          xb, wqb, wob, ctab, stab, mkf, mfg);
    gemm_qkv_kernel<<<dim3(32, 24), 512, 0, stream>>>(xb, wqb, qkv_b, ctab, stab, qg, kg, vt);
    attn_kernel<<<dim3(512), 256, 0, stream>>>(qg, kg, vt, mkf, mfg, yb);
    gemm_out_kernel<<<dim3(32, 16), 256, 0, stream>>>(yb, wob, out_b, out);
}

// Round 22
// 96.078 us; speedup vs baseline: 1.2286x; 1.1612x over previous
//
#include <hip/hip_runtime.h>
#include <hip/hip_bf16.h>

typedef __bf16 bf16;
typedef __bf16 bf16x4 __attribute__((ext_vector_type(4)));
typedef __bf16 bf16x8 __attribute__((ext_vector_type(8)));
typedef float f32x4 __attribute__((ext_vector_type(4)));
typedef unsigned int u32x4 __attribute__((ext_vector_type(4)));

#define T_LEN 2048
#define NHEAD 16
#define DHEAD 64
#define CDIM 1024
#define NB 2

__device__ __forceinline__ void g2l16(const void* g, void* l) {
    __builtin_amdgcn_global_load_lds(
        (const __attribute__((address_space(1))) unsigned int*)g,
        (__attribute__((address_space(3))) unsigned int*)l, 16, 0, 0);
}

// native 2^x (v_exp_f32): inputs are base-2 logits
__device__ __forceinline__ float fexp2(float x) {
    float r;
    asm("v_exp_f32 %0, %1" : "=v"(r) : "v"(x));
    return r;
}

// stage a 64-row x 128-byte tile into linear LDS with XOR-swizzled content
// (source pre-swizzle, m173). 256 threads: two 16B chunks each.
__device__ __forceinline__ void stage_swz256(const bf16* __restrict__ g, size_t gstride,
                                             bf16* lds, int t) {
#pragma unroll
    for (int c = 0; c < 2; c++) {
        int off = c * 4096 + t * 16;           // phys byte offset in LDS (0..8191)
        int row = off >> 7;
        int lcol = (off & 127) ^ ((row & 7) << 4);
        g2l16(g + (size_t)row * gstride + (lcol >> 1), (char*)lds + off);
    }
}

__device__ __forceinline__ bf16x8 rd_swz(const bf16* lds, int row, int colB) {
    return *(const bf16x8*)((const char*)lds + row * 128 + (colB ^ ((row & 7) << 4)));
}

// ---------- fused prep: fp32->bf16 x3 + RoPE tables + mask (+block flags) ----------
__global__ __launch_bounds__(256) void prep_kernel(
    const float* __restrict__ x, const float* __restrict__ qkv_w,
    const float* __restrict__ out_w, const int* __restrict__ am,
    bf16* __restrict__ xb, bf16* __restrict__ wqb, bf16* __restrict__ wob,
    float* __restrict__ ct, float* __restrict__ st, float* __restrict__ mf,
    int* __restrict__ mflag) {
    int bid = blockIdx.x;
    if (bid < 4096) {                         // converts (block-uniform section)
        int i = bid * 256 + threadIdx.x;
        const float* src; bf16* dst; int j;
        if (i < 524288)      { src = x;     dst = xb;  j = i; }
        else if (i < 917504) { src = qkv_w; dst = wqb; j = i - 524288; }
        else                 { src = out_w; dst = wob; j = i - 917504; }
        const float4* p = (const float4*)src + (size_t)j * 2;
        float4 a = p[0], b = p[1];
        bf16x8 o;
        o[0] = (bf16)a.x; o[1] = (bf16)a.y; o[2] = (bf16)a.z; o[3] = (bf16)a.w;
        o[4] = (bf16)b.x; o[5] = (bf16)b.y; o[6] = (bf16)b.z; o[7] = (bf16)b.w;
        ((bf16x8*)dst)[j] = o;
    } else if (bid < 4608) {                  // RoPE tables
        int i = (bid - 4096) * 256 + threadIdx.x;   // i = t*64 + d
        int t = i >> 6, d = i & 63;
        float ex = (float)(2 * (d & 31)) / 64.0f;
        float inv = powf(10000.0f, -ex);
        float ang = (float)t * inv;
        ct[i] = cosf(ang);
        st[i] = sinf(ang);
    } else {                                  // key mask -> additive float + flags
        int i = (bid - 4608) * 256 + threadIdx.x;
        int v = am[i];
        mf[i] = (v != 0) ? 0.0f : -1e30f;
        unsigned long long bz = __ballot(v == 0);   // wave covers 64 consecutive i
        if ((threadIdx.x & 63) == 0) mflag[i >> 6] = (bz != 0) ? 1 : 0;
    }
}

// ---------- QKV GEMM: 128x128 tile, 8 waves, DOUBLE-BUFFERED (1 barrier/iter) ----------
__global__ __launch_bounds__(512, 4) void gemm_qkv_kernel(
    const bf16* __restrict__ xb, const bf16* __restrict__ wb,
    const float* __restrict__ bias,
    const float* __restrict__ ct, const float* __restrict__ st,
    bf16* __restrict__ qg, bf16* __restrict__ kg, bf16* __restrict__ vt) {
    __shared__ __align__(16) bf16 smem[2][2 * 128 * 64];   // 2 bufs x 32 KB
    int m0 = blockIdx.x * 128, n0 = blockIdx.y * 128;
    int t = threadIdx.x, w = t >> 6, l = t & 63;
    int wm = w & 3, wn = w >> 2;                // 4 M-strips x 2 N-halves
    int l15 = l & 15, lhi = l >> 4;
    f32x4 acc[2][4] = {};
    // prologue: stage k0=0 into buf 0
#pragma unroll
    for (int c = 0; c < 2; c++) {
        int off = c * 8192 + t * 16;
        int row = off >> 7;
        int lcol = (off & 127) ^ ((row & 7) << 4);
        g2l16(xb + (size_t)(m0 + row) * CDIM + (lcol >> 1), (char*)smem[0] + off);
        g2l16(wb + (size_t)(n0 + row) * CDIM + (lcol >> 1), (char*)(smem[0] + 128 * 64) + off);
    }
    __syncthreads();
    int cur = 0;
    for (int k0 = 0; k0 < CDIM; k0 += 64) {
        if (k0 + 64 < CDIM) {                   // issue prefetch of next K-tile
#pragma unroll
            for (int c = 0; c < 2; c++) {
                int off = c * 8192 + t * 16;
                int row = off >> 7;
                int lcol = (off & 127) ^ ((row & 7) << 4);
                g2l16(xb + (size_t)(m0 + row) * CDIM + k0 + 64 + (lcol >> 1),
                      (char*)smem[cur ^ 1] + off);
                g2l16(wb + (size_t)(n0 + row) * CDIM + k0 + 64 + (lcol >> 1),
                      (char*)(smem[cur ^ 1] + 128 * 64) + off);
            }
        }
        bf16* sA = smem[cur];
        bf16* sB = smem[cur] + 128 * 64;
#pragma unroll
        for (int ks = 0; ks < 2; ks++) {
            bf16x8 af[2], bfr[4];
#pragma unroll
            for (int mt = 0; mt < 2; mt++)
                af[mt] = rd_swz(sA, wm * 32 + mt * 16 + l15, ks * 64 + lhi * 16);
#pragma unroll
            for (int nt = 0; nt < 4; nt++)
                bfr[nt] = rd_swz(sB, wn * 64 + nt * 16 + l15, ks * 64 + lhi * 16);
#pragma unroll
            for (int mt = 0; mt < 2; mt++)
#pragma unroll
                for (int nt = 0; nt < 4; nt++)
                    acc[mt][nt] = __builtin_amdgcn_mfma_f32_16x16x32_bf16(
                        af[mt], bfr[nt], acc[mt][nt], 0, 0, 0);
        }
        __syncthreads();                        // one barrier/iter
        cur ^= 1;
    }
    int bb = m0 >> 11, tt0 = m0 & 2047;         // block never crosses batch
    if (n0 >= 2048) {
        // ---- V block (2 heads): bias + LDS transpose + coalesced store ----
        bf16* sT = (bf16*)smem;                 // [64 d][136 tt] = 17.4 KB
#pragma unroll
        for (int pass = 0; pass < 2; pass++) {
            __syncthreads();
            if (wn == pass) {
#pragma unroll
                for (int nt = 0; nt < 4; nt++) {
                    int dl = nt * 16 + l15;     // 0..63 within head
                    float cb = bias[n0 + pass * 64 + dl];
#pragma unroll
                    for (int mt = 0; mt < 2; mt++) {
                        bf16x4 pv;
#pragma unroll
                        for (int r = 0; r < 4; r++) pv[r] = (bf16)(acc[mt][nt][r] + cb);
                        *(bf16x4*)(sT + dl * 136 + wm * 32 + mt * 16 + lhi * 4) = pv;
                    }
                }
            }
            __syncthreads();
            int h_p = ((n0 & 1023) >> 6) + pass;
            size_t vbase = ((size_t)(bb * NHEAD + h_p)) * T_LEN * DHEAD + tt0;
#pragma unroll
            for (int c = 0; c < 2; c++) {
                int cid = c * 512 + t;
                int d = cid >> 4, ch = cid & 15;
                *(bf16x8*)(vt + vbase + (size_t)d * T_LEN + ch * 8) =
                    *(const bf16x8*)(sT + d * 136 + ch * 8);
            }
        }
        return;
    }
    // ---- Q/K block: bias + RoPE, [B][H][T][Dh] store ----
    int sec = n0 >> 10;                         // 0=Q 1=K (block-uniform)
    bf16* og = (sec == 0) ? qg : kg;
    float oscale = (sec == 0) ? 0.125f * 1.44269504f : 1.0f;
#pragma unroll
    for (int nt = 0; nt < 4; nt++) {
        int col = n0 + wn * 64 + nt * 16 + l15;
        int cc = col & 1023;
        int h = cc >> 6, d = cc & 63;
        float cb = bias[col];
        size_t hb = ((size_t)(bb * NHEAD + h)) * T_LEN * DHEAD;
#pragma unroll
        for (int mt = 0; mt < 2; mt++) {
#pragma unroll
            for (int r = 0; r < 4; r++) {
                int tt = tt0 + wm * 32 + mt * 16 + lhi * 4 + r;
                float v = acc[mt][nt][r] + cb;
                float p = __shfl_xor(v, 1);
                float cs = ct[tt * 64 + d], sn = st[tt * 64 + d];
                float o = (d & 1) ? (v * cs + p * sn) : (v * cs - p * sn);
                og[hb + (size_t)tt * DHEAD + d] = (bf16)(o * oscale);
            }
        }
    }
}

// ---------- flash attention: 4-wave blocks, QBLK=64, shift-free softmax,
// TWO q-tiles sequentially per block (qt=pos then 31-pos -> uniform 33 iters;
// keeps 2 blocks x 4 waves resident 100% of the time — R21's m-block sharing
// left CUs running one block solo for most iters). Phase-2 staging is issued
// before the phase-1 epilogue so its HBM latency hides under the stores. ----------
__global__ __launch_bounds__(256, 4) void attn_kernel(
    const bf16* __restrict__ qg, const bf16* __restrict__ kg, const bf16* __restrict__ vt,
    const float* __restrict__ maskf, const int* __restrict__ mflag,
    bf16* __restrict__ yb) {
    __shared__ __align__(16) bf16 sK[2][64 * 64];
    __shared__ __align__(16) bf16 sV[2][64 * 64];
    int lin = blockIdx.x;                 // 512 blocks
    int xcd = lin & 7, idx = lin >> 3;    // idx 0..63
    int group = idx >> 4, pos = idx & 15;
    int pair = xcd * 4 + group;           // 0..31
    int h = pair & 15, b = pair >> 4;
    int t = threadIdx.x, w = t >> 6, l = t & 63;
    int l15 = l & 15, lhi = l >> 4;
    const size_t head_off = ((size_t)(b * NHEAD + h)) * T_LEN * DHEAD;
    const bf16* qb = qg + head_off;
    const bf16* kb = kg + head_off;
    const bf16* vb = vt + head_off;                 // [Dh][T]
    const float* mrow = maskf + b * T_LEN;
    const int* mfl = mflag + b * (T_LEN / 64);
    const u32x4 onesu = {0x3F803F80u, 0x3F803F80u, 0x3F803F80u, 0x3F803F80u};
    const bf16x8 ones8 = __builtin_bit_cast(bf16x8, onesu);
    stage_swz256(kb, DHEAD, sK[0], t);              // phase-0 kv0=0 staging
    stage_swz256(vb, T_LEN, sV[0], t);
#pragma unroll 1
    for (int ph = 0; ph < 2; ph++) {
        int qt = ph ? (31 - pos) : pos;
        int q0 = qt * 64;
        const int wq0 = q0 + w * 16;                // wave's first q row
        const int qrow_l = wq0 + l15;               // this lane's q row
        bf16x8 qf[2];
        qf[0] = *(const bf16x8*)(qb + (size_t)qrow_l * DHEAD + lhi * 8);
        qf[1] = *(const bf16x8*)(qb + (size_t)qrow_l * DHEAD + 32 + lhi * 8);
        f32x4 lsv = {};                             // row-layout ls (ones-MFMA)
        f32x4 accy[4] = {};
        __syncthreads();                            // kv0=0 staging complete
        int cur = 0;
        for (int kv0 = 0; kv0 <= q0; kv0 += 64) {   // qt+1 tiles
            if (kv0 + 64 <= q0) {                   // prefetch next tile
                stage_swz256(kb + (size_t)(kv0 + 64) * DHEAD, DHEAD, sK[cur ^ 1], t);
                stage_swz256(vb + (kv0 + 64), T_LEN, sV[cur ^ 1], t);
            }
            if (kv0 <= wq0 + 15) {                  // wave has unmasked work
                // S^T = K Q^T: lane holds q = l15, kv = c*16 + lhi*4 + r
                f32x4 s[4] = {};
                __builtin_amdgcn_s_setprio(1);
#pragma unroll
                for (int c = 0; c < 4; c++)
#pragma unroll
                    for (int ks = 0; ks < 2; ks++) {
                        bf16x8 kf = rd_swz(sK[cur], c * 16 + l15, ks * 64 + lhi * 16);
                        s[c] = __builtin_amdgcn_mfma_f32_16x16x32_bf16(kf, qf[ks], s[c], 0, 0, 0);
                    }
                __builtin_amdgcn_s_setprio(0);
                bool diag = (kv0 + 63 > wq0);       // tile crosses strip's diagonal
                int needmask = mfl[kv0 >> 6];       // uniform scalar load
                if (needmask || diag) {             // mask/causal adds (rare path)
#pragma unroll
                    for (int c = 0; c < 4; c++) {
                        float mpv[4] = {0.f, 0.f, 0.f, 0.f};
                        if (needmask) {
                            float4 mq = *(const float4*)(mrow + kv0 + c * 16 + lhi * 4);
                            mpv[0] = mq.x; mpv[1] = mq.y; mpv[2] = mq.z; mpv[3] = mq.w;
                        }
#pragma unroll
                        for (int r = 0; r < 4; r++) {
                            float sv = s[c][r] + mpv[r];
                            if (diag && (kv0 + c * 16 + lhi * 4 + r > qrow_l)) sv = -1e30f;
                            s[c][r] = sv;
                        }
                    }
                }
                // shift-free P = 2^s (scale cancels in accy/ls)
#pragma unroll
                for (int c = 0; c < 4; c++)
#pragma unroll
                    for (int r = 0; r < 4; r++) s[c][r] = fexp2(s[c][r]);
                // PV: in-register P relayout; ls via ones-MFMA
                __builtin_amdgcn_s_setprio(1);
#pragma unroll
                for (int g2 = 0; g2 < 2; g2++) {
                    unsigned a0, a1, b0, b1;
                    asm("v_cvt_pk_bf16_f32 %0, %1, %2" : "=v"(a0) : "v"(s[2 * g2][0]), "v"(s[2 * g2][1]));
                    asm("v_cvt_pk_bf16_f32 %0, %1, %2" : "=v"(a1) : "v"(s[2 * g2][2]), "v"(s[2 * g2][3]));
                    asm("v_cvt_pk_bf16_f32 %0, %1, %2" : "=v"(b0) : "v"(s[2 * g2 + 1][0]), "v"(s[2 * g2 + 1][1]));
                    asm("v_cvt_pk_bf16_f32 %0, %1, %2" : "=v"(b1) : "v"(s[2 * g2 + 1][2]), "v"(s[2 * g2 + 1][3]));
                    asm("v_permlane32_swap_b32 %0, %1" : "+v"(a0), "+v"(b0));
                    asm("v_permlane16_swap_b32 %0, %1" : "+v"(a0), "+v"(b0));
                    asm("v_permlane32_swap_b32 %0, %1" : "+v"(a1), "+v"(b1));
                    asm("v_permlane16_swap_b32 %0, %1" : "+v"(a1), "+v"(b1));
                    u32x4 pu;
                    pu[0] = a0; pu[1] = a1; pu[2] = b0; pu[3] = b1;
                    bf16x8 pv = __builtin_bit_cast(bf16x8, pu);
                    lsv = __builtin_amdgcn_mfma_f32_16x16x32_bf16(pv, ones8, lsv, 0, 0, 0);
#pragma unroll
                    for (int dt = 0; dt < 4; dt++) {
                        bf16x8 vf = rd_swz(sV[cur], dt * 16 + l15, g2 * 64 + lhi * 16);
                        accy[dt] = __builtin_amdgcn_mfma_f32_16x16x32_bf16(pv, vf, accy[dt], 0, 0, 0);
                    }
                }
                __builtin_amdgcn_s_setprio(0);
            }
            __syncthreads();
            cur ^= 1;
        }
        // issue phase-2 kv0=0 staging now (all LDS reads done after the loop's
        // final barrier); its latency hides under the epilogue stores below.
        if (ph == 0) {
            stage_swz256(kb, DHEAD, sK[0], t);
            stage_swz256(vb, T_LEN, sV[0], t);
        }
#pragma unroll
        for (int r = 0; r < 4; r++) {
            float inv = lsv[r] > 0.f ? 1.0f / lsv[r] : 0.0f;   // lane-local
            int rowt = wq0 + lhi * 4 + r;
            size_t obase = ((size_t)(b * T_LEN + rowt)) * CDIM + (size_t)h * DHEAD;
#pragma unroll
            for (int dt = 0; dt < 4; dt++)
                yb[obase + dt * 16 + l15] = (bf16)(accy[dt][r] * inv);
        }
    }
}

// ---------- output GEMM: 128x64 tiles, DOUBLE-BUFFERED (1 barrier/iter) ----------
__global__ __launch_bounds__(256) void gemm_out_kernel(
    const bf16* __restrict__ yb, const bf16* __restrict__ wb,
    const float* __restrict__ bias, float* __restrict__ out) {
    __shared__ __align__(16) bf16 smem[2][128 * 64 + 64 * 64];  // 2 x 24 KB
    int m0 = blockIdx.x * 128, n0 = blockIdx.y * 64;
    int t = threadIdx.x, w = t >> 6, l = t & 63;
    int wm = w >> 1, wn = w & 1;
    int l15 = l & 15, lhi = l >> 4;
    f32x4 acc[4][2] = {};
#pragma unroll
    for (int i = 0; i < 4; i++) {               // prologue stage k0=0
        int off = i * 4096 + t * 16;
        int row = off >> 7;
        int lcol = (off & 127) ^ ((row & 7) << 4);
        g2l16(yb + (size_t)(m0 + row) * CDIM + (lcol >> 1), (char*)smem[0] + off);
        if (i < 2)
            g2l16(wb + (size_t)(n0 + row) * CDIM + (lcol >> 1),
                  (char*)(smem[0] + 128 * 64) + off);
    }
    __syncthreads();
    int cur = 0;
    for (int k0 = 0; k0 < CDIM; k0 += 64) {
        if (k0 + 64 < CDIM) {
#pragma unroll
            for (int i = 0; i < 4; i++) {
                int off = i * 4096 + t * 16;
                int row = off >> 7;
                int lcol = (off & 127) ^ ((row & 7) << 4);
                g2l16(yb + (size_t)(m0 + row) * CDIM + k0 + 64 + (lcol >> 1),
                      (char*)smem[cur ^ 1] + off);
                if (i < 2)
                    g2l16(wb + (size_t)(n0 + row) * CDIM + k0 + 64 + (lcol >> 1),
                          (char*)(smem[cur ^ 1] + 128 * 64) + off);
            }
        }
        bf16* sA = smem[cur];
        bf16* sB = smem[cur] + 128 * 64;
#pragma unroll
        for (int ks = 0; ks < 2; ks++) {
            bf16x8 af[4], bfr[2];
#pragma unroll
            for (int mt = 0; mt < 4; mt++)
                af[mt] = rd_swz(sA, wm * 64 + mt * 16 + l15, ks * 64 + lhi * 16);
#pragma unroll
            for (int nt = 0; nt < 2; nt++)
                bfr[nt] = rd_swz(sB, wn * 32 + nt * 16 + l15, ks * 64 + lhi * 16);
#pragma unroll
            for (int mt = 0; mt < 4; mt++)
#pragma unroll
                for (int nt = 0; nt < 2; nt++)
                    acc[mt][nt] = __builtin_amdgcn_mfma_f32_16x16x32_bf16(
                        af[mt], bfr[nt], acc[mt][nt], 0, 0, 0);
        }
        __syncthreads();
        cur ^= 1;
    }
#pragma unroll
    for (int nt = 0; nt < 2; nt++) {
        int col = n0 + wn * 32 + nt * 16 + l15;
        float cb = bias[col];
#pragma unroll
        for (int mt = 0; mt < 4; mt++) {
#pragma unroll
            for (int r = 0; r < 4; r++) {
                int rowm = m0 + wm * 64 + mt * 16 + lhi * 4 + r;
                out[(size_t)rowm * CDIM + col] = acc[mt][nt][r] + cb;
            }
        }
    }
}

extern "C" void kernel_launch(void* const* d_in, const int* in_sizes, int n_in,
                              void* d_out, int out_size, void* d_ws, size_t ws_size,
                              hipStream_t stream) {
    const float* x      = (const float*)d_in[0];
    const int*   amask  = (const int*)d_in[1];
    const float* qkv_w  = (const float*)d_in[2];
    const float* qkv_b  = (const float*)d_in[3];
    const float* out_w  = (const float*)d_in[4];
    const float* out_b  = (const float*)d_in[5];
    float* out = (float*)d_out;

    char* ws = (char*)d_ws;
    bf16* xb  = (bf16*)(ws);                        // 8 MB   (4096x1024)
    bf16* wqb = (bf16*)(ws + (8ull  << 20));        // 6 MB   (3072x1024)
    bf16* wob = (bf16*)(ws + (14ull << 20));        // 2 MB   (1024x1024)
    bf16* qg  = (bf16*)(ws + (16ull << 20));        // 8 MB   [B,H,T,Dh]
    bf16* kg  = (bf16*)(ws + (24ull << 20));        // 8 MB   [B,H,T,Dh]
    bf16* vt  = (bf16*)(ws + (32ull << 20));        // 8 MB   [B,H,Dh,T]
    bf16* yb  = (bf16*)(ws + (40ull << 20));        // 8 MB   (4096x1024)
    float* ctab = (float*)(ws + (48ull << 20));     // 512 KB (2048x64)
    float* stab = (float*)(ws + (48ull << 20) + (1ull << 19));
    float* mkf  = (float*)(ws + (49ull << 20));     // 16 KB  (2x2048 floats)
    int*   mfg  = (int*)(ws + (49ull << 20) + (16ull << 10));  // 256 B (64 ints)

    prep_kernel<<<4624, 256, 0, stream>>>(x, qkv_w, out_w, amask,
                                          xb, wqb, wob, ctab, stab, mkf, mfg);
    gemm_qkv_kernel<<<dim3(32, 24), 512, 0, stream>>>(xb, wqb, qkv_b, ctab, stab, qg, kg, vt);
    attn_kernel<<<dim3(512), 256, 0, stream>>>(qg, kg, vt, mkf, mfg, yb);
    gemm_out_kernel<<<dim3(32, 16), 256, 0, stream>>>(yb, wob, out_b, out);
}